// Round 10
// baseline (975.919 us; speedup 1.0000x reference)
//
#include <hip/hip_runtime.h>

// ---------- helpers ----------

__device__ __forceinline__ float red16(float p) {
    p += __shfl_xor(p, 1, 64);
    p += __shfl_xor(p, 2, 64);
    p += __shfl_xor(p, 4, 64);
    p += __shfl_xor(p, 8, 64);
    return p;
}

__device__ __forceinline__ float bf2f(unsigned short v) {
    return __uint_as_float(((unsigned int)v) << 16);
}
__device__ __forceinline__ unsigned short f2bf(float f) {
    unsigned int u = __float_as_uint(f);
    u = (u + 0x7FFFu + ((u >> 16) & 1u)) >> 16;
    return (unsigned short)u;
}

__device__ __forceinline__ void kgfma(float4& a, float wj, ushort4 u, float4 v) {
    a.x = fmaf(wj, bf2f(u.x) * v.x, a.x);
    a.y = fmaf(wj, bf2f(u.y) * v.y, a.y);
    a.z = fmaf(wj, bf2f(u.z) * v.z, a.z);
    a.w = fmaf(wj, bf2f(u.w) * v.w, a.w);
}
__device__ __forceinline__ void uifma(float4& a, float wj, ushort4 u) {
    a.x = fmaf(wj, bf2f(u.x), a.x);
    a.y = fmaf(wj, bf2f(u.y), a.y);
    a.z = fmaf(wj, bf2f(u.z), a.z);
    a.w = fmaf(wj, bf2f(u.w), a.w);
}

// ---------- setup kernels ----------

// 640 threads: thread = r*64+k. w_all[r][k] = sum_c W_Q[k][c]*relemb[r][c]
// (r<9); w_all[9][k] = sum_c W_UI[k][c]*relemb[etype[E-1]-1][c].
__global__ void compute_w_kernel(const float* __restrict__ WQ,
                                 const float* __restrict__ WUI,
                                 const float* __restrict__ relemb,
                                 const int* __restrict__ etype, int Ekg,
                                 float* __restrict__ w_all) {
    int tid = threadIdx.x;
    if (tid >= 640) return;
    int r = tid >> 6, k = tid & 63;
    const float* M = (r == 9) ? WUI : WQ;
    int rr = (r == 9) ? (etype[Ekg - 1] - 1) : r;
    float acc = 0.f;
#pragma unroll
    for (int c = 0; c < 64; ++c)
        acc = fmaf(M[k * 64 + c], relemb[rr * 64 + c], acc);
    w_all[r * 64 + k] = acc;
}

// merged tables: blocks [0,nbe) entity S (10 dots) + bf16 copy of E;
// [nbe,nbe+nbu) user su
__global__ void tables_kernel(const float* __restrict__ E, int n_ent, int nbe,
                              const float* __restrict__ U, int n_usr,
                              const float* __restrict__ w_all,
                              float* __restrict__ S, float* __restrict__ su,
                              unsigned short* __restrict__ Ebf) {
    __shared__ float4 w4[160];
    for (int i = threadIdx.x; i < 160; i += blockDim.x)
        w4[i] = ((const float4*)w_all)[i];
    __syncthreads();
    int l16 = threadIdx.x & 15;
    if ((int)blockIdx.x < nbe) {
        int row = blockIdx.x * 16 + (threadIdx.x >> 4);
        float4 ev = make_float4(0.f, 0.f, 0.f, 0.f);
        if (row < n_ent) ev = ((const float4*)E)[(size_t)row * 16 + l16];
        if (row < n_ent) {
            ushort4 eb;
            eb.x = f2bf(ev.x); eb.y = f2bf(ev.y);
            eb.z = f2bf(ev.z); eb.w = f2bf(ev.w);
            ((ushort4*)Ebf)[(size_t)row * 16 + l16] = eb;
        }
#pragma unroll
        for (int r = 0; r < 10; ++r) {
            float4 wv = w4[r * 16 + l16];
            float p = ev.x * wv.x + ev.y * wv.y + ev.z * wv.z + ev.w * wv.w;
            p = red16(p);
            if (l16 == 0 && row < n_ent) S[(size_t)row * 10 + r] = p;
        }
    } else {
        int row = (blockIdx.x - nbe) * 16 + (threadIdx.x >> 4);
        float4 ev = make_float4(0.f, 0.f, 0.f, 0.f);
        if (row < n_usr) ev = ((const float4*)U)[(size_t)row * 16 + l16];
        float4 wv = w4[144 + l16];
        float p = ev.x * wv.x + ev.y * wv.y + ev.z * wv.z + ev.w * wv.w;
        p = red16(p);
        if (l16 == 0 && row < n_usr) su[row] = p;
    }
}

// ---------- CSR build (merged ent+usr) ----------

__global__ void hist2_kernel(const int* __restrict__ ia, int Ea,
                             unsigned int* __restrict__ dega,
                             const int* __restrict__ ib, int Eb,
                             unsigned int* __restrict__ degb) {
    int e = blockIdx.x * blockDim.x + threadIdx.x;
    if (e < Ea) atomicAdd(&dega[ia[e]], 1u);
    else if (e < Ea + Eb) atomicAdd(&degb[ib[e - Ea]], 1u);
}

#define SCAN_CHUNK 2048
#define BUCK_SHIFT 8

__device__ __forceinline__ void scan1_body(const unsigned int* deg, int n,
                                           unsigned int* bsums, int blk) {
    int base = blk * SCAN_CHUNK;
    int tid = threadIdx.x;
    unsigned int s = 0;
#pragma unroll
    for (int j = 0; j < 8; ++j) {
        int i = base + tid * 8 + j;
        if (i < n) s += deg[i];
    }
#pragma unroll
    for (int off = 32; off > 0; off >>= 1)
        s += __shfl_xor(s, off, 64);
    __shared__ unsigned int wsm[4];
    if ((tid & 63) == 0) wsm[tid >> 6] = s;
    __syncthreads();
    if (tid == 0) bsums[blk] = wsm[0] + wsm[1] + wsm[2] + wsm[3];
}

__global__ void scan_pass1(const unsigned int* __restrict__ dega, int na, int nba,
                           unsigned int* __restrict__ bsa,
                           const unsigned int* __restrict__ degb, int nb_,
                           unsigned int* __restrict__ bsb) {
    if ((int)blockIdx.x < nba) scan1_body(dega, na, bsa, blockIdx.x);
    else scan1_body(degb, nb_, bsb, blockIdx.x - nba);
}

__device__ __forceinline__ void scan2_body(unsigned int* bsums, int nb) {
    __shared__ unsigned int tmp[1024];
    int tid = threadIdx.x;
    unsigned int v = (tid < nb) ? bsums[tid] : 0u;
    tmp[tid] = v;
    __syncthreads();
    for (int s = 1; s < 1024; s <<= 1) {
        unsigned int add = (tid >= s) ? tmp[tid - s] : 0u;
        __syncthreads();
        tmp[tid] += add;
        __syncthreads();
    }
    if (tid < nb) bsums[tid] = tmp[tid] - v; // exclusive
}

__global__ void scan_pass2(unsigned int* __restrict__ bsa, int nba,
                           unsigned int* __restrict__ bsb, int nbb) {
    if (blockIdx.x == 0) scan2_body(bsa, nba);
    else scan2_body(bsb, nbb);
}

__device__ __forceinline__ void scan3_body(const unsigned int* deg, int n,
                                           const unsigned int* bsums,
                                           unsigned int* off, int blk) {
    int base = blk * SCAN_CHUNK;
    int tid = threadIdx.x;
    int lane = tid & 63, wv = tid >> 6;
    unsigned int x[8];
    unsigned int s = 0;
#pragma unroll
    for (int j = 0; j < 8; ++j) {
        int i = base + tid * 8 + j;
        x[j] = (i < n) ? deg[i] : 0u;
        s += x[j];
    }
    unsigned int sc = s;
#pragma unroll
    for (int o = 1; o < 64; o <<= 1) {
        unsigned int t = __shfl_up(sc, o, 64);
        if (lane >= o) sc += t;
    }
    __shared__ unsigned int wtot[4];
    if (lane == 63) wtot[wv] = sc;
    __syncthreads();
    unsigned int woff = 0;
    for (int w = 0; w < wv; ++w) woff += wtot[w];
    unsigned int run = bsums[blk] + woff + (sc - s);
#pragma unroll
    for (int j = 0; j < 8; ++j) {
        int i = base + tid * 8 + j;
        run += x[j];
        if (i < n) off[i + 1] = run;
    }
    if (blk == 0 && tid == 0) off[0] = 0;
}

__global__ void scan_pass3(const unsigned int* __restrict__ dega, int na, int nba,
                           const unsigned int* __restrict__ bsa,
                           unsigned int* __restrict__ offa,
                           const unsigned int* __restrict__ degb, int nb_,
                           const unsigned int* __restrict__ bsb,
                           unsigned int* __restrict__ offb) {
    if ((int)blockIdx.x < nba) scan3_body(dega, na, bsa, offa, blockIdx.x);
    else scan3_body(degb, nb_, bsb, offb, blockIdx.x - nba);
}

// bucket cursors: bcur[b] = off[b << BUCK_SHIFT]
__global__ void bucket_init_kernel(const unsigned int* __restrict__ off_e,
                                   int nbk_e,
                                   const unsigned int* __restrict__ off_u,
                                   int nbk_u,
                                   unsigned int* __restrict__ bcur_e,
                                   unsigned int* __restrict__ bcur_u) {
    int i = blockIdx.x * blockDim.x + threadIdx.x;
    if (i < nbk_e) bcur_e[i] = off_e[i << BUCK_SHIFT];
    else if (i < nbk_e + nbk_u) {
        int j = i - nbk_e;
        bcur_u[j] = off_u[j << BUCK_SHIFT];
    }
}

// phase 1: partition edges into per-bucket contiguous regions (exact sizes)
__global__ void bucketize_kernel(const int* __restrict__ head,
                                 const int* __restrict__ tail,
                                 const int* __restrict__ etype, int Ekg,
                                 unsigned int* __restrict__ bcur_e,
                                 unsigned long long* __restrict__ tmp_e,
                                 const int* __restrict__ uu,
                                 const int* __restrict__ ii,
                                 const float* __restrict__ iw, int Eui,
                                 unsigned int* __restrict__ bcur_u,
                                 ulonglong2* __restrict__ tmp_u) {
    int e = blockIdx.x * blockDim.x + threadIdx.x;
    if (e < Ekg) {
        int h = head[e];
        unsigned int pos = atomicAdd(&bcur_e[h >> BUCK_SHIFT], 1u);
        unsigned int pay = (unsigned int)tail[e] |
                           (((unsigned int)(etype[e] - 1)) << 20);
        tmp_e[pos] = ((unsigned long long)(unsigned int)h << 32) | pay;
    } else if (e < Ekg + Eui) {
        int e2 = e - Ekg;
        int u = uu[e2];
        unsigned int pos = atomicAdd(&bcur_u[u >> BUCK_SHIFT], 1u);
        ulonglong2 v;
        v.x = ((unsigned long long)(unsigned int)u << 32) |
              (unsigned int)ii[e2];
        v.y = (unsigned long long)__float_as_uint(iw[e2]);
        tmp_u[pos] = v;
    }
}

// phase 2: within-bucket regroup to exact CSR slots (writes stay in a
// ~7KB window per block since tmp is bucket-grouped)
__global__ void scatter_final_kernel(const unsigned long long* __restrict__ tmp_e,
                                     int Ekg,
                                     const unsigned int* __restrict__ off_e,
                                     unsigned int* __restrict__ cur_e,
                                     unsigned int* __restrict__ packed,
                                     const ulonglong2* __restrict__ tmp_u,
                                     int Eui,
                                     const unsigned int* __restrict__ off_u,
                                     unsigned int* __restrict__ cur_u,
                                     unsigned long long* __restrict__ sorted_iw) {
    int e = blockIdx.x * blockDim.x + threadIdx.x;
    if (e < Ekg) {
        unsigned long long v = tmp_e[e];
        unsigned int h = (unsigned int)(v >> 32);
        unsigned int fpos = off_e[h] + atomicAdd(&cur_e[h], 1u);
        packed[fpos] = (unsigned int)v;
    } else if (e < Ekg + Eui) {
        ulonglong2 v = tmp_u[e - Ekg];
        unsigned int u = (unsigned int)(v.x >> 32);
        unsigned int fpos = off_u[u] + atomicAdd(&cur_u[u], 1u);
        sorted_iw[fpos] = (v.y << 32) | (unsigned int)v.x;
    }
}

// ---------- fused per-hop aggregation: kg blocks then ui blocks ----------
// 16-lane group per destination row; chunked lane-parallel scoring; 4x
// unrolled bf16 row-gather (128 B/row). No max-subtraction (scores
// bounded; exp safe in fp32 — verified R7/R8).

__global__ void hop_fused_kernel(
    const unsigned int* __restrict__ off_e,
    const unsigned int* __restrict__ packed,
    const float* __restrict__ S,
    const float* __restrict__ relemb,
    int n_ent, int nbe,
    unsigned short* __restrict__ eagg_bf, float* __restrict__ Snext,
    float* __restrict__ res_e, const float* __restrict__ res_init_e,
    const unsigned int* __restrict__ off_u,
    const unsigned long long* __restrict__ sorted_iw,
    const float* __restrict__ su, int n_usr,
    float* __restrict__ sunext,
    float* __restrict__ res_u, const float* __restrict__ res_init_u,
    const unsigned short* __restrict__ Ebf,
    const float* __restrict__ w_all) {
    __shared__ float4 rel4[144]; // 9 x 16
    __shared__ float4 w4[160];   // 10 x 16
    for (int i = threadIdx.x; i < 144; i += blockDim.x)
        rel4[i] = ((const float4*)relemb)[i];
    for (int i = threadIdx.x; i < 160; i += blockDim.x)
        w4[i] = ((const float4*)w_all)[i];
    __syncthreads();

    int lane = threadIdx.x & 63;
    int l16 = lane & 15;
    int gbase = lane & 48; // group base within wave for shfl

    if ((int)blockIdx.x < nbe) {
        int h = blockIdx.x * 16 + (threadIdx.x >> 4);
        if (h >= n_ent) return;
        unsigned int s0 = off_e[h], s1 = off_e[h + 1];
        float shv = (l16 < 10) ? S[(size_t)h * 10 + l16] : 0.f;

        float4 a0 = make_float4(0.f, 0.f, 0.f, 0.f);
        float4 a1 = make_float4(0.f, 0.f, 0.f, 0.f);
        float4 a2 = make_float4(0.f, 0.f, 0.f, 0.f);
        float4 a3 = make_float4(0.f, 0.f, 0.f, 0.f);
        float wsum = 0.f;
        for (unsigned int base = s0; base < s1; base += 16) {
            unsigned int rem = s1 - base;
            unsigned int c = rem < 16u ? rem : 16u;
            unsigned int pk = (l16 < (int)c) ? packed[base + l16] : 0u;
            int t = pk & 0xFFFFF, r = pk >> 20;
            float st = S[(size_t)t * 10 + r];
            float q = __shfl(shv, gbase + r, 64);
            float wg = (l16 < (int)c) ? __expf(q + st) : 0.f;
            wsum += red16(wg);
            unsigned int j = 0;
            for (; j + 4 <= c; j += 4) {
                unsigned int p0 = (unsigned int)__shfl((int)pk, gbase + (int)j, 64);
                unsigned int p1 = (unsigned int)__shfl((int)pk, gbase + (int)j + 1, 64);
                unsigned int p2 = (unsigned int)__shfl((int)pk, gbase + (int)j + 2, 64);
                unsigned int p3 = (unsigned int)__shfl((int)pk, gbase + (int)j + 3, 64);
                float w0 = __shfl(wg, gbase + (int)j, 64);
                float w1 = __shfl(wg, gbase + (int)j + 1, 64);
                float w2 = __shfl(wg, gbase + (int)j + 2, 64);
                float w3 = __shfl(wg, gbase + (int)j + 3, 64);
                int t0 = p0 & 0xFFFFF, t1 = p1 & 0xFFFFF;
                int t2 = p2 & 0xFFFFF, t3 = p3 & 0xFFFFF;
                ushort4 u0 = ((const ushort4*)Ebf)[(size_t)t0 * 16 + l16];
                ushort4 u1 = ((const ushort4*)Ebf)[(size_t)t1 * 16 + l16];
                ushort4 u2 = ((const ushort4*)Ebf)[(size_t)t2 * 16 + l16];
                ushort4 u3 = ((const ushort4*)Ebf)[(size_t)t3 * 16 + l16];
                kgfma(a0, w0, u0, rel4[(p0 >> 20) * 16 + l16]);
                kgfma(a1, w1, u1, rel4[(p1 >> 20) * 16 + l16]);
                kgfma(a2, w2, u2, rel4[(p2 >> 20) * 16 + l16]);
                kgfma(a3, w3, u3, rel4[(p3 >> 20) * 16 + l16]);
            }
            for (; j < c; ++j) {
                unsigned int p0 = (unsigned int)__shfl((int)pk, gbase + (int)j, 64);
                float w0 = __shfl(wg, gbase + (int)j, 64);
                int t0 = p0 & 0xFFFFF;
                ushort4 u0 = ((const ushort4*)Ebf)[(size_t)t0 * 16 + l16];
                kgfma(a0, w0, u0, rel4[(p0 >> 20) * 16 + l16]);
            }
        }
        float4 acc = make_float4(a0.x + a1.x + a2.x + a3.x,
                                 a0.y + a1.y + a2.y + a3.y,
                                 a0.z + a1.z + a2.z + a3.z,
                                 a0.w + a1.w + a2.w + a3.w);
        float inv = 1.f / (wsum + 1e-16f);
        float4 y = make_float4(acc.x * inv, acc.y * inv, acc.z * inv, acc.w * inv);
        float ss = red16(y.x * y.x + y.y * y.y + y.z * y.z + y.w * y.w);
        float sinv = 1.f / fmaxf(sqrtf(ss), 1e-12f);
        y.x *= sinv; y.y *= sinv; y.z *= sinv; y.w *= sinv;

        size_t ro = (size_t)h * 16 + l16;
        if (eagg_bf) {
            ushort4 yb;
            yb.x = f2bf(y.x); yb.y = f2bf(y.y);
            yb.z = f2bf(y.z); yb.w = f2bf(y.w);
            ((ushort4*)eagg_bf)[ro] = yb;
        }
        float4 b4 = res_init_e ? ((const float4*)res_init_e)[ro]
                               : ((const float4*)res_e)[ro];
        ((float4*)res_e)[ro] = make_float4(b4.x + y.x, b4.y + y.y,
                                           b4.z + y.z, b4.w + y.w);
        if (Snext) {
#pragma unroll
            for (int r2 = 0; r2 < 10; ++r2) {
                float4 wv = w4[r2 * 16 + l16];
                float p = red16(y.x * wv.x + y.y * wv.y + y.z * wv.z + y.w * wv.w);
                if (l16 == 0) Snext[(size_t)h * 10 + r2] = p;
            }
        }
    } else {
        int u = (blockIdx.x - nbe) * 16 + (threadIdx.x >> 4);
        if (u >= n_usr) return;
        unsigned int s0 = off_u[u], s1 = off_u[u + 1];
        float squ = su[u];

        float4 a0 = make_float4(0.f, 0.f, 0.f, 0.f);
        float4 a1 = make_float4(0.f, 0.f, 0.f, 0.f);
        float4 a2 = make_float4(0.f, 0.f, 0.f, 0.f);
        float4 a3 = make_float4(0.f, 0.f, 0.f, 0.f);
        float wsum = 0.f;
        for (unsigned int base = s0; base < s1; base += 16) {
            unsigned int rem = s1 - base;
            unsigned int c = rem < 16u ? rem : 16u;
            unsigned int iv = 0; float wg = 0.f, cw = 0.f;
            if (l16 < (int)c) {
                unsigned long long t8 = sorted_iw[base + l16];
                iv = (unsigned int)t8;
                float sw = __uint_as_float((unsigned int)(t8 >> 32));
                wg = __expf(squ + S[(size_t)iv * 10 + 9]);
                cw = wg * sw;
            }
            wsum += red16(wg);
            unsigned int j = 0;
            for (; j + 4 <= c; j += 4) {
                unsigned int i0 = (unsigned int)__shfl((int)iv, gbase + (int)j, 64);
                unsigned int i1 = (unsigned int)__shfl((int)iv, gbase + (int)j + 1, 64);
                unsigned int i2 = (unsigned int)__shfl((int)iv, gbase + (int)j + 2, 64);
                unsigned int i3 = (unsigned int)__shfl((int)iv, gbase + (int)j + 3, 64);
                float w0 = __shfl(cw, gbase + (int)j, 64);
                float w1 = __shfl(cw, gbase + (int)j + 1, 64);
                float w2 = __shfl(cw, gbase + (int)j + 2, 64);
                float w3 = __shfl(cw, gbase + (int)j + 3, 64);
                ushort4 u0 = ((const ushort4*)Ebf)[(size_t)i0 * 16 + l16];
                ushort4 u1 = ((const ushort4*)Ebf)[(size_t)i1 * 16 + l16];
                ushort4 u2 = ((const ushort4*)Ebf)[(size_t)i2 * 16 + l16];
                ushort4 u3 = ((const ushort4*)Ebf)[(size_t)i3 * 16 + l16];
                uifma(a0, w0, u0);
                uifma(a1, w1, u1);
                uifma(a2, w2, u2);
                uifma(a3, w3, u3);
            }
            for (; j < c; ++j) {
                unsigned int i0 = (unsigned int)__shfl((int)iv, gbase + (int)j, 64);
                float w0 = __shfl(cw, gbase + (int)j, 64);
                ushort4 u0 = ((const ushort4*)Ebf)[(size_t)i0 * 16 + l16];
                uifma(a0, w0, u0);
            }
        }
        float4 acc = make_float4(a0.x + a1.x + a2.x + a3.x,
                                 a0.y + a1.y + a2.y + a3.y,
                                 a0.z + a1.z + a2.z + a3.z,
                                 a0.w + a1.w + a2.w + a3.w);
        float inv = 1.f / (wsum + 1e-16f);
        float4 y = make_float4(acc.x * inv, acc.y * inv, acc.z * inv, acc.w * inv);
        float ss = red16(y.x * y.x + y.y * y.y + y.z * y.z + y.w * y.w);
        float sinv = 1.f / fmaxf(sqrtf(ss), 1e-12f);
        y.x *= sinv; y.y *= sinv; y.z *= sinv; y.w *= sinv;

        size_t ro = (size_t)u * 16 + l16;
        float4 b4 = res_init_u ? ((const float4*)res_init_u)[ro]
                               : ((const float4*)res_u)[ro];
        ((float4*)res_u)[ro] = make_float4(b4.x + y.x, b4.y + y.y,
                                           b4.z + y.z, b4.w + y.w);
        if (sunext) {
            float4 wv = w4[144 + l16];
            float p = red16(y.x * wv.x + y.y * wv.y + y.z * wv.z + y.w * wv.w);
            if (l16 == 0) sunext[u] = p;
        }
    }
}

// ---------- launch ----------

extern "C" void kernel_launch(void* const* d_in, const int* in_sizes, int n_in,
                              void* d_out, int out_size, void* d_ws, size_t ws_size,
                              hipStream_t stream) {
    const float* user_emb   = (const float*)d_in[0];
    const float* entity_emb = (const float*)d_in[1];
    const int*   edge_index = (const int*)d_in[2];
    const int*   edge_type  = (const int*)d_in[3];
    const int*   inter_edge = (const int*)d_in[4];
    const float* inter_w    = (const float*)d_in[5];
    const float* relemb     = (const float*)d_in[6];
    const float* WQ         = (const float*)d_in[7];
    const float* WUI        = (const float*)d_in[8];

    const int C = 64;
    const int n_usr = in_sizes[0] / C;
    const int n_ent = in_sizes[1] / C;
    const int Ekg   = in_sizes[3];
    const int Eui   = in_sizes[5];
    const int* head = edge_index;
    const int* tail = edge_index + Ekg;
    const int* uu   = inter_edge;
    const int* ii   = inter_edge + Eui;

    float* ws = (float*)d_ws;
    float* w_all = ws;                          ws += 640;
    float* S0    = ws;                          ws += (size_t)n_ent * 10;
    float* S1    = ws;                          ws += (size_t)n_ent * 10;
    float* su0   = ws;                          ws += n_usr;
    float* su1   = ws;                          ws += n_usr;
    unsigned int* deg_ent = (unsigned int*)ws;  ws += n_ent;   // also cursor
    unsigned int* deg_usr = (unsigned int*)ws;  ws += n_usr;   // also cursor
    unsigned int* off_ent = (unsigned int*)ws;  ws += n_ent + 1;
    unsigned int* off_usr = (unsigned int*)ws;  ws += n_usr + 1;
    unsigned int* bsum_e  = (unsigned int*)ws;  ws += 1024;
    unsigned int* bsum_u  = (unsigned int*)ws;  ws += 1024;
    unsigned int* bcur_e  = (unsigned int*)ws;  ws += 1024;
    unsigned int* bcur_u  = (unsigned int*)ws;  ws += 1024;
    unsigned int* packed  = (unsigned int*)ws;  ws += Ekg;

    uintptr_t p16 = ((uintptr_t)ws + 15) & ~(uintptr_t)15;
    unsigned long long* sorted_iw = (unsigned long long*)p16;
    p16 += (size_t)Eui * 8;
    unsigned long long* tmp_e = (unsigned long long*)p16;
    p16 += (size_t)Ekg * 8;
    ulonglong2* tmp_u = (ulonglong2*)p16;
    p16 += (size_t)Eui * 16;
    unsigned short* ebf0 = (unsigned short*)p16;
    p16 += (size_t)n_ent * 64 * 2;
    unsigned short* ebf1 = (unsigned short*)p16;

    float* out_ent = (float*)d_out;
    float* out_usr = out_ent + (size_t)n_ent * C;

    compute_w_kernel<<<1, 640, 0, stream>>>(WQ, WUI, relemb, edge_type, Ekg, w_all);

    // ---- CSR build (edges static across hops) ----
    hipMemsetAsync(deg_ent, 0, (size_t)(n_ent + n_usr) * sizeof(unsigned int), stream);
    hist2_kernel<<<(Ekg + Eui + 255) / 256, 256, 0, stream>>>(
        head, Ekg, deg_ent, uu, Eui, deg_usr);

    int nb_e = (n_ent + SCAN_CHUNK - 1) / SCAN_CHUNK;
    int nb_u = (n_usr + SCAN_CHUNK - 1) / SCAN_CHUNK;
    scan_pass1<<<nb_e + nb_u, 256, 0, stream>>>(deg_ent, n_ent, nb_e, bsum_e,
                                                deg_usr, n_usr, bsum_u);
    scan_pass2<<<2, 1024, 0, stream>>>(bsum_e, nb_e, bsum_u, nb_u);
    scan_pass3<<<nb_e + nb_u, 256, 0, stream>>>(deg_ent, n_ent, nb_e, bsum_e, off_ent,
                                                deg_usr, n_usr, bsum_u, off_usr);

    // ---- two-phase locality-preserving scatter ----
    int nbk_e = (n_ent + (1 << BUCK_SHIFT) - 1) >> BUCK_SHIFT;
    int nbk_u = (n_usr + (1 << BUCK_SHIFT) - 1) >> BUCK_SHIFT;
    bucket_init_kernel<<<(nbk_e + nbk_u + 255) / 256, 256, 0, stream>>>(
        off_ent, nbk_e, off_usr, nbk_u, bcur_e, bcur_u);
    bucketize_kernel<<<(Ekg + Eui + 255) / 256, 256, 0, stream>>>(
        head, tail, edge_type, Ekg, bcur_e, tmp_e,
        uu, ii, inter_w, Eui, bcur_u, tmp_u);
    hipMemsetAsync(deg_ent, 0, (size_t)(n_ent + n_usr) * sizeof(unsigned int), stream);
    scatter_final_kernel<<<(Ekg + Eui + 255) / 256, 256, 0, stream>>>(
        tmp_e, Ekg, off_ent, deg_ent, packed,
        tmp_u, Eui, off_usr, deg_usr, sorted_iw);

    int nbe = (n_ent + 15) / 16;
    int nbu = (n_usr + 15) / 16;

    // ---- hop-0 tables + bf16 copy of entity_emb ----
    tables_kernel<<<nbe + nbu, 256, 0, stream>>>(
        entity_emb, n_ent, nbe, user_emb, n_usr, w_all, S0, su0, ebf0);

    // ---- hop 0: emits S1/su1 + bf16 agg for hop 1; res = init + y ----
    hop_fused_kernel<<<nbe + nbu, 256, 0, stream>>>(
        off_ent, packed, S0, relemb, n_ent, nbe,
        ebf1, S1, out_ent, entity_emb,
        off_usr, sorted_iw, su0, n_usr,
        su1, out_usr, user_emb,
        ebf0, w_all);

    // ---- hop 1: res += y (agg outputs dead -> skipped) ----
    hop_fused_kernel<<<nbe + nbu, 256, 0, stream>>>(
        off_ent, packed, S1, relemb, n_ent, nbe,
        nullptr, nullptr, out_ent, nullptr,
        off_usr, sorted_iw, su1, n_usr,
        nullptr, out_usr, nullptr,
        ebf1, w_all);
}

// Round 11
// 389.761 us; speedup vs baseline: 2.5039x; 2.5039x over previous
//
#include <hip/hip_runtime.h>

// ---------- helpers ----------

__device__ __forceinline__ float red16(float p) {
    p += __shfl_xor(p, 1, 64);
    p += __shfl_xor(p, 2, 64);
    p += __shfl_xor(p, 4, 64);
    p += __shfl_xor(p, 8, 64);
    return p;
}

__device__ __forceinline__ float bf2f(unsigned short v) {
    return __uint_as_float(((unsigned int)v) << 16);
}
__device__ __forceinline__ unsigned short f2bf(float f) {
    unsigned int u = __float_as_uint(f);
    u = (u + 0x7FFFu + ((u >> 16) & 1u)) >> 16;
    return (unsigned short)u;
}

__device__ __forceinline__ void kgfma(float4& a, float wj, ushort4 u, float4 v) {
    a.x = fmaf(wj, bf2f(u.x) * v.x, a.x);
    a.y = fmaf(wj, bf2f(u.y) * v.y, a.y);
    a.z = fmaf(wj, bf2f(u.z) * v.z, a.z);
    a.w = fmaf(wj, bf2f(u.w) * v.w, a.w);
}
__device__ __forceinline__ void uifma(float4& a, float wj, ushort4 u) {
    a.x = fmaf(wj, bf2f(u.x), a.x);
    a.y = fmaf(wj, bf2f(u.y), a.y);
    a.z = fmaf(wj, bf2f(u.z), a.z);
    a.w = fmaf(wj, bf2f(u.w), a.w);
}

// ---------- setup: compute_w (block 0) + hist-with-rank (rest) ----------
// rank[e] = atomicAdd(deg[dst],1) is recorded so the later scatter needs
// NO atomics (off[dst]+rank[e] is an exact unique slot).

__global__ void setup_kernel(const float* __restrict__ WQ,
                             const float* __restrict__ WUI,
                             const float* __restrict__ relemb,
                             const int* __restrict__ etype, int Ekg,
                             float* __restrict__ w_all,
                             const int* __restrict__ head,
                             unsigned int* __restrict__ deg_ent,
                             unsigned int* __restrict__ rank_e,
                             const int* __restrict__ uu, int Eui,
                             unsigned int* __restrict__ deg_usr,
                             unsigned int* __restrict__ rank_u) {
    if (blockIdx.x == 0) {
        for (int tid = threadIdx.x; tid < 640; tid += blockDim.x) {
            int r = tid >> 6, k = tid & 63;
            const float* M = (r == 9) ? WUI : WQ;
            int rr = (r == 9) ? (etype[Ekg - 1] - 1) : r;
            float acc = 0.f;
#pragma unroll
            for (int c = 0; c < 64; ++c)
                acc = fmaf(M[k * 64 + c], relemb[rr * 64 + c], acc);
            w_all[r * 64 + k] = acc;
        }
        return;
    }
    int e = (blockIdx.x - 1) * blockDim.x + threadIdx.x;
    if (e < Ekg) {
        rank_e[e] = atomicAdd(&deg_ent[head[e]], 1u);
    } else if (e < Ekg + Eui) {
        int e2 = e - Ekg;
        rank_u[e2] = atomicAdd(&deg_usr[uu[e2]], 1u);
    }
}

// ---------- scans (merged ent+usr) ----------

#define SCAN_CHUNK 2048

__device__ __forceinline__ void scan1_body(const unsigned int* deg, int n,
                                           unsigned int* bsums, int blk) {
    int base = blk * SCAN_CHUNK;
    int tid = threadIdx.x;
    unsigned int s = 0;
#pragma unroll
    for (int j = 0; j < 8; ++j) {
        int i = base + tid * 8 + j;
        if (i < n) s += deg[i];
    }
#pragma unroll
    for (int off = 32; off > 0; off >>= 1)
        s += __shfl_xor(s, off, 64);
    __shared__ unsigned int wsm[4];
    if ((tid & 63) == 0) wsm[tid >> 6] = s;
    __syncthreads();
    if (tid == 0) bsums[blk] = wsm[0] + wsm[1] + wsm[2] + wsm[3];
}

__global__ void scan_pass1(const unsigned int* __restrict__ dega, int na, int nba,
                           unsigned int* __restrict__ bsa,
                           const unsigned int* __restrict__ degb, int nb_,
                           unsigned int* __restrict__ bsb) {
    if ((int)blockIdx.x < nba) scan1_body(dega, na, bsa, blockIdx.x);
    else scan1_body(degb, nb_, bsb, blockIdx.x - nba);
}

__device__ __forceinline__ void scan2_body(unsigned int* bsums, int nb) {
    __shared__ unsigned int tmp[1024];
    int tid = threadIdx.x;
    unsigned int v = (tid < nb) ? bsums[tid] : 0u;
    tmp[tid] = v;
    __syncthreads();
    for (int s = 1; s < 1024; s <<= 1) {
        unsigned int add = (tid >= s) ? tmp[tid - s] : 0u;
        __syncthreads();
        tmp[tid] += add;
        __syncthreads();
    }
    if (tid < nb) bsums[tid] = tmp[tid] - v; // exclusive
}

__global__ void scan_pass2(unsigned int* __restrict__ bsa, int nba,
                           unsigned int* __restrict__ bsb, int nbb) {
    if (blockIdx.x == 0) scan2_body(bsa, nba);
    else scan2_body(bsb, nbb);
}

__device__ __forceinline__ void scan3_body(const unsigned int* deg, int n,
                                           const unsigned int* bsums,
                                           unsigned int* off, int blk) {
    int base = blk * SCAN_CHUNK;
    int tid = threadIdx.x;
    int lane = tid & 63, wv = tid >> 6;
    unsigned int x[8];
    unsigned int s = 0;
#pragma unroll
    for (int j = 0; j < 8; ++j) {
        int i = base + tid * 8 + j;
        x[j] = (i < n) ? deg[i] : 0u;
        s += x[j];
    }
    unsigned int sc = s;
#pragma unroll
    for (int o = 1; o < 64; o <<= 1) {
        unsigned int t = __shfl_up(sc, o, 64);
        if (lane >= o) sc += t;
    }
    __shared__ unsigned int wtot[4];
    if (lane == 63) wtot[wv] = sc;
    __syncthreads();
    unsigned int woff = 0;
    for (int w = 0; w < wv; ++w) woff += wtot[w];
    unsigned int run = bsums[blk] + woff + (sc - s);
#pragma unroll
    for (int j = 0; j < 8; ++j) {
        int i = base + tid * 8 + j;
        run += x[j];
        if (i < n) off[i + 1] = run;
    }
    if (blk == 0 && tid == 0) off[0] = 0;
}

__global__ void scan_pass3(const unsigned int* __restrict__ dega, int na, int nba,
                           const unsigned int* __restrict__ bsa,
                           unsigned int* __restrict__ offa,
                           const unsigned int* __restrict__ degb, int nb_,
                           const unsigned int* __restrict__ bsb,
                           unsigned int* __restrict__ offb) {
    if ((int)blockIdx.x < nba) scan3_body(dega, na, bsa, offa, blockIdx.x);
    else scan3_body(degb, nb_, bsb, offb, blockIdx.x - nba);
}

// ---------- merged atomic-free scatter + tables ----------
// blocks [0,nsc): scatter (pure random stores, no RMW — rank precomputed).
// blocks [nsc,nsc+nbe): entity S table + bf16 copy; rest: user su table.
// The streaming tables work overlaps the scatter's memory latency.

__global__ void scatter_tables_kernel(
    const int* __restrict__ head, const int* __restrict__ tail,
    const int* __restrict__ etype, int Ekg,
    const unsigned int* __restrict__ off_e,
    const unsigned int* __restrict__ rank_e,
    unsigned int* __restrict__ packed,
    const int* __restrict__ uu, const int* __restrict__ ii,
    const float* __restrict__ iw, int Eui,
    const unsigned int* __restrict__ off_u,
    const unsigned int* __restrict__ rank_u,
    unsigned long long* __restrict__ sorted_iw,
    int nsc,
    const float* __restrict__ E, int n_ent, int nbe,
    const float* __restrict__ U, int n_usr,
    const float* __restrict__ w_all,
    float* __restrict__ S, float* __restrict__ su,
    unsigned short* __restrict__ Ebf) {
    if ((int)blockIdx.x < nsc) {
        int e = blockIdx.x * blockDim.x + threadIdx.x;
        if (e < Ekg) {
            int h = head[e];
            unsigned int pos = off_e[h] + rank_e[e];
            packed[pos] = (unsigned int)tail[e] |
                          (((unsigned int)(etype[e] - 1)) << 20);
        } else if (e < Ekg + Eui) {
            int e2 = e - Ekg;
            int u = uu[e2];
            unsigned int pos = off_u[u] + rank_u[e2];
            sorted_iw[pos] =
                ((unsigned long long)__float_as_uint(iw[e2]) << 32) |
                (unsigned int)ii[e2];
        }
        return;
    }
    __shared__ float4 w4[160];
    for (int i = threadIdx.x; i < 160; i += blockDim.x)
        w4[i] = ((const float4*)w_all)[i];
    __syncthreads();
    int l16 = threadIdx.x & 15;
    int bb = blockIdx.x - nsc;
    if (bb < nbe) {
        int row = bb * 16 + (threadIdx.x >> 4);
        float4 ev = make_float4(0.f, 0.f, 0.f, 0.f);
        if (row < n_ent) {
            ev = ((const float4*)E)[(size_t)row * 16 + l16];
            ushort4 eb;
            eb.x = f2bf(ev.x); eb.y = f2bf(ev.y);
            eb.z = f2bf(ev.z); eb.w = f2bf(ev.w);
            ((ushort4*)Ebf)[(size_t)row * 16 + l16] = eb;
        }
#pragma unroll
        for (int r = 0; r < 10; ++r) {
            float4 wv = w4[r * 16 + l16];
            float p = ev.x * wv.x + ev.y * wv.y + ev.z * wv.z + ev.w * wv.w;
            p = red16(p);
            if (l16 == 0 && row < n_ent) S[(size_t)row * 10 + r] = p;
        }
    } else {
        int row = (bb - nbe) * 16 + (threadIdx.x >> 4);
        float4 ev = make_float4(0.f, 0.f, 0.f, 0.f);
        if (row < n_usr) ev = ((const float4*)U)[(size_t)row * 16 + l16];
        float4 wv = w4[144 + l16];
        float p = ev.x * wv.x + ev.y * wv.y + ev.z * wv.z + ev.w * wv.w;
        p = red16(p);
        if (l16 == 0 && row < n_usr) su[row] = p;
    }
}

// ---------- fused per-hop aggregation: kg blocks then ui blocks ----------
// 16-lane group per destination row; chunked lane-parallel scoring; 4x
// unrolled bf16 row-gather (128 B/row). No max-subtraction (scores
// bounded; exp safe in fp32 — verified R7/R8).

__global__ void hop_fused_kernel(
    const unsigned int* __restrict__ off_e,
    const unsigned int* __restrict__ packed,
    const float* __restrict__ S,
    const float* __restrict__ relemb,
    int n_ent, int nbe,
    unsigned short* __restrict__ eagg_bf, float* __restrict__ Snext,
    float* __restrict__ res_e, const float* __restrict__ res_init_e,
    const unsigned int* __restrict__ off_u,
    const unsigned long long* __restrict__ sorted_iw,
    const float* __restrict__ su, int n_usr,
    float* __restrict__ sunext,
    float* __restrict__ res_u, const float* __restrict__ res_init_u,
    const unsigned short* __restrict__ Ebf,
    const float* __restrict__ w_all) {
    __shared__ float4 rel4[144]; // 9 x 16
    __shared__ float4 w4[160];   // 10 x 16
    for (int i = threadIdx.x; i < 144; i += blockDim.x)
        rel4[i] = ((const float4*)relemb)[i];
    for (int i = threadIdx.x; i < 160; i += blockDim.x)
        w4[i] = ((const float4*)w_all)[i];
    __syncthreads();

    int lane = threadIdx.x & 63;
    int l16 = lane & 15;
    int gbase = lane & 48; // group base within wave for shfl

    if ((int)blockIdx.x < nbe) {
        int h = blockIdx.x * 16 + (threadIdx.x >> 4);
        if (h >= n_ent) return;
        unsigned int s0 = off_e[h], s1 = off_e[h + 1];
        float shv = (l16 < 10) ? S[(size_t)h * 10 + l16] : 0.f;

        float4 a0 = make_float4(0.f, 0.f, 0.f, 0.f);
        float4 a1 = make_float4(0.f, 0.f, 0.f, 0.f);
        float4 a2 = make_float4(0.f, 0.f, 0.f, 0.f);
        float4 a3 = make_float4(0.f, 0.f, 0.f, 0.f);
        float wsum = 0.f;
        for (unsigned int base = s0; base < s1; base += 16) {
            unsigned int rem = s1 - base;
            unsigned int c = rem < 16u ? rem : 16u;
            unsigned int pk = (l16 < (int)c) ? packed[base + l16] : 0u;
            int t = pk & 0xFFFFF, r = pk >> 20;
            float st = S[(size_t)t * 10 + r];
            float q = __shfl(shv, gbase + r, 64);
            float wg = (l16 < (int)c) ? __expf(q + st) : 0.f;
            wsum += red16(wg);
            unsigned int j = 0;
            for (; j + 4 <= c; j += 4) {
                unsigned int p0 = (unsigned int)__shfl((int)pk, gbase + (int)j, 64);
                unsigned int p1 = (unsigned int)__shfl((int)pk, gbase + (int)j + 1, 64);
                unsigned int p2 = (unsigned int)__shfl((int)pk, gbase + (int)j + 2, 64);
                unsigned int p3 = (unsigned int)__shfl((int)pk, gbase + (int)j + 3, 64);
                float w0 = __shfl(wg, gbase + (int)j, 64);
                float w1 = __shfl(wg, gbase + (int)j + 1, 64);
                float w2 = __shfl(wg, gbase + (int)j + 2, 64);
                float w3 = __shfl(wg, gbase + (int)j + 3, 64);
                int t0 = p0 & 0xFFFFF, t1 = p1 & 0xFFFFF;
                int t2 = p2 & 0xFFFFF, t3 = p3 & 0xFFFFF;
                ushort4 u0 = ((const ushort4*)Ebf)[(size_t)t0 * 16 + l16];
                ushort4 u1 = ((const ushort4*)Ebf)[(size_t)t1 * 16 + l16];
                ushort4 u2 = ((const ushort4*)Ebf)[(size_t)t2 * 16 + l16];
                ushort4 u3 = ((const ushort4*)Ebf)[(size_t)t3 * 16 + l16];
                kgfma(a0, w0, u0, rel4[(p0 >> 20) * 16 + l16]);
                kgfma(a1, w1, u1, rel4[(p1 >> 20) * 16 + l16]);
                kgfma(a2, w2, u2, rel4[(p2 >> 20) * 16 + l16]);
                kgfma(a3, w3, u3, rel4[(p3 >> 20) * 16 + l16]);
            }
            for (; j < c; ++j) {
                unsigned int p0 = (unsigned int)__shfl((int)pk, gbase + (int)j, 64);
                float w0 = __shfl(wg, gbase + (int)j, 64);
                int t0 = p0 & 0xFFFFF;
                ushort4 u0 = ((const ushort4*)Ebf)[(size_t)t0 * 16 + l16];
                kgfma(a0, w0, u0, rel4[(p0 >> 20) * 16 + l16]);
            }
        }
        float4 acc = make_float4(a0.x + a1.x + a2.x + a3.x,
                                 a0.y + a1.y + a2.y + a3.y,
                                 a0.z + a1.z + a2.z + a3.z,
                                 a0.w + a1.w + a2.w + a3.w);
        float inv = 1.f / (wsum + 1e-16f);
        float4 y = make_float4(acc.x * inv, acc.y * inv, acc.z * inv, acc.w * inv);
        float ss = red16(y.x * y.x + y.y * y.y + y.z * y.z + y.w * y.w);
        float sinv = 1.f / fmaxf(sqrtf(ss), 1e-12f);
        y.x *= sinv; y.y *= sinv; y.z *= sinv; y.w *= sinv;

        size_t ro = (size_t)h * 16 + l16;
        if (eagg_bf) {
            ushort4 yb;
            yb.x = f2bf(y.x); yb.y = f2bf(y.y);
            yb.z = f2bf(y.z); yb.w = f2bf(y.w);
            ((ushort4*)eagg_bf)[ro] = yb;
        }
        float4 b4 = res_init_e ? ((const float4*)res_init_e)[ro]
                               : ((const float4*)res_e)[ro];
        ((float4*)res_e)[ro] = make_float4(b4.x + y.x, b4.y + y.y,
                                           b4.z + y.z, b4.w + y.w);
        if (Snext) {
#pragma unroll
            for (int r2 = 0; r2 < 10; ++r2) {
                float4 wv = w4[r2 * 16 + l16];
                float p = red16(y.x * wv.x + y.y * wv.y + y.z * wv.z + y.w * wv.w);
                if (l16 == 0) Snext[(size_t)h * 10 + r2] = p;
            }
        }
    } else {
        int u = (blockIdx.x - nbe) * 16 + (threadIdx.x >> 4);
        if (u >= n_usr) return;
        unsigned int s0 = off_u[u], s1 = off_u[u + 1];
        float squ = su[u];

        float4 a0 = make_float4(0.f, 0.f, 0.f, 0.f);
        float4 a1 = make_float4(0.f, 0.f, 0.f, 0.f);
        float4 a2 = make_float4(0.f, 0.f, 0.f, 0.f);
        float4 a3 = make_float4(0.f, 0.f, 0.f, 0.f);
        float wsum = 0.f;
        for (unsigned int base = s0; base < s1; base += 16) {
            unsigned int rem = s1 - base;
            unsigned int c = rem < 16u ? rem : 16u;
            unsigned int iv = 0; float wg = 0.f, cw = 0.f;
            if (l16 < (int)c) {
                unsigned long long t8 = sorted_iw[base + l16];
                iv = (unsigned int)t8;
                float sw = __uint_as_float((unsigned int)(t8 >> 32));
                wg = __expf(squ + S[(size_t)iv * 10 + 9]);
                cw = wg * sw;
            }
            wsum += red16(wg);
            unsigned int j = 0;
            for (; j + 4 <= c; j += 4) {
                unsigned int i0 = (unsigned int)__shfl((int)iv, gbase + (int)j, 64);
                unsigned int i1 = (unsigned int)__shfl((int)iv, gbase + (int)j + 1, 64);
                unsigned int i2 = (unsigned int)__shfl((int)iv, gbase + (int)j + 2, 64);
                unsigned int i3 = (unsigned int)__shfl((int)iv, gbase + (int)j + 3, 64);
                float w0 = __shfl(cw, gbase + (int)j, 64);
                float w1 = __shfl(cw, gbase + (int)j + 1, 64);
                float w2 = __shfl(cw, gbase + (int)j + 2, 64);
                float w3 = __shfl(cw, gbase + (int)j + 3, 64);
                ushort4 u0 = ((const ushort4*)Ebf)[(size_t)i0 * 16 + l16];
                ushort4 u1 = ((const ushort4*)Ebf)[(size_t)i1 * 16 + l16];
                ushort4 u2 = ((const ushort4*)Ebf)[(size_t)i2 * 16 + l16];
                ushort4 u3 = ((const ushort4*)Ebf)[(size_t)i3 * 16 + l16];
                uifma(a0, w0, u0);
                uifma(a1, w1, u1);
                uifma(a2, w2, u2);
                uifma(a3, w3, u3);
            }
            for (; j < c; ++j) {
                unsigned int i0 = (unsigned int)__shfl((int)iv, gbase + (int)j, 64);
                float w0 = __shfl(cw, gbase + (int)j, 64);
                ushort4 u0 = ((const ushort4*)Ebf)[(size_t)i0 * 16 + l16];
                uifma(a0, w0, u0);
            }
        }
        float4 acc = make_float4(a0.x + a1.x + a2.x + a3.x,
                                 a0.y + a1.y + a2.y + a3.y,
                                 a0.z + a1.z + a2.z + a3.z,
                                 a0.w + a1.w + a2.w + a3.w);
        float inv = 1.f / (wsum + 1e-16f);
        float4 y = make_float4(acc.x * inv, acc.y * inv, acc.z * inv, acc.w * inv);
        float ss = red16(y.x * y.x + y.y * y.y + y.z * y.z + y.w * y.w);
        float sinv = 1.f / fmaxf(sqrtf(ss), 1e-12f);
        y.x *= sinv; y.y *= sinv; y.z *= sinv; y.w *= sinv;

        size_t ro = (size_t)u * 16 + l16;
        float4 b4 = res_init_u ? ((const float4*)res_init_u)[ro]
                               : ((const float4*)res_u)[ro];
        ((float4*)res_u)[ro] = make_float4(b4.x + y.x, b4.y + y.y,
                                           b4.z + y.z, b4.w + y.w);
        if (sunext) {
            float4 wv = w4[144 + l16];
            float p = red16(y.x * wv.x + y.y * wv.y + y.z * wv.z + y.w * wv.w);
            if (l16 == 0) sunext[u] = p;
        }
    }
}

// ---------- launch ----------

extern "C" void kernel_launch(void* const* d_in, const int* in_sizes, int n_in,
                              void* d_out, int out_size, void* d_ws, size_t ws_size,
                              hipStream_t stream) {
    const float* user_emb   = (const float*)d_in[0];
    const float* entity_emb = (const float*)d_in[1];
    const int*   edge_index = (const int*)d_in[2];
    const int*   edge_type  = (const int*)d_in[3];
    const int*   inter_edge = (const int*)d_in[4];
    const float* inter_w    = (const float*)d_in[5];
    const float* relemb     = (const float*)d_in[6];
    const float* WQ         = (const float*)d_in[7];
    const float* WUI        = (const float*)d_in[8];

    const int C = 64;
    const int n_usr = in_sizes[0] / C;
    const int n_ent = in_sizes[1] / C;
    const int Ekg   = in_sizes[3];
    const int Eui   = in_sizes[5];
    const int* head = edge_index;
    const int* tail = edge_index + Ekg;
    const int* uu   = inter_edge;
    const int* ii   = inter_edge + Eui;

    float* ws = (float*)d_ws;
    float* w_all = ws;                          ws += 640;
    float* S0    = ws;                          ws += (size_t)n_ent * 10;
    float* S1    = ws;                          ws += (size_t)n_ent * 10;
    float* su0   = ws;                          ws += n_usr;
    float* su1   = ws;                          ws += n_usr;
    unsigned int* deg_ent = (unsigned int*)ws;  ws += n_ent;
    unsigned int* deg_usr = (unsigned int*)ws;  ws += n_usr;
    unsigned int* off_ent = (unsigned int*)ws;  ws += n_ent + 1;
    unsigned int* off_usr = (unsigned int*)ws;  ws += n_usr + 1;
    unsigned int* bsum_e  = (unsigned int*)ws;  ws += 1024;
    unsigned int* bsum_u  = (unsigned int*)ws;  ws += 1024;
    unsigned int* rank_e  = (unsigned int*)ws;  ws += Ekg;
    unsigned int* rank_u  = (unsigned int*)ws;  ws += Eui;
    unsigned int* packed  = (unsigned int*)ws;  ws += Ekg;

    uintptr_t p16 = ((uintptr_t)ws + 15) & ~(uintptr_t)15;
    unsigned long long* sorted_iw = (unsigned long long*)p16;
    p16 += (size_t)Eui * 8;
    unsigned short* ebf0 = (unsigned short*)p16;
    p16 += (size_t)n_ent * 64 * 2;
    unsigned short* ebf1 = (unsigned short*)p16;

    float* out_ent = (float*)d_out;
    float* out_usr = out_ent + (size_t)n_ent * C;

    // ---- setup: compute_w + hist-with-rank ----
    hipMemsetAsync(deg_ent, 0, (size_t)(n_ent + n_usr) * sizeof(unsigned int), stream);
    setup_kernel<<<1 + (Ekg + Eui + 255) / 256, 256, 0, stream>>>(
        WQ, WUI, relemb, edge_type, Ekg, w_all,
        head, deg_ent, rank_e, uu, Eui, deg_usr, rank_u);

    // ---- scans ----
    int nb_e = (n_ent + SCAN_CHUNK - 1) / SCAN_CHUNK;
    int nb_u = (n_usr + SCAN_CHUNK - 1) / SCAN_CHUNK;
    scan_pass1<<<nb_e + nb_u, 256, 0, stream>>>(deg_ent, n_ent, nb_e, bsum_e,
                                                deg_usr, n_usr, bsum_u);
    scan_pass2<<<2, 1024, 0, stream>>>(bsum_e, nb_e, bsum_u, nb_u);
    scan_pass3<<<nb_e + nb_u, 256, 0, stream>>>(deg_ent, n_ent, nb_e, bsum_e, off_ent,
                                                deg_usr, n_usr, bsum_u, off_usr);

    // ---- atomic-free scatter merged with hop-0 tables ----
    int nsc = (Ekg + Eui + 255) / 256;
    int nbe = (n_ent + 15) / 16;
    int nbu = (n_usr + 15) / 16;
    scatter_tables_kernel<<<nsc + nbe + nbu, 256, 0, stream>>>(
        head, tail, edge_type, Ekg, off_ent, rank_e, packed,
        uu, ii, inter_w, Eui, off_usr, rank_u, sorted_iw, nsc,
        entity_emb, n_ent, nbe, user_emb, n_usr, w_all, S0, su0, ebf0);

    // ---- hop 0: emits S1/su1 + bf16 agg for hop 1; res = init + y ----
    hop_fused_kernel<<<nbe + nbu, 256, 0, stream>>>(
        off_ent, packed, S0, relemb, n_ent, nbe,
        ebf1, S1, out_ent, entity_emb,
        off_usr, sorted_iw, su0, n_usr,
        su1, out_usr, user_emb,
        ebf0, w_all);

    // ---- hop 1: res += y (agg outputs dead -> skipped) ----
    hop_fused_kernel<<<nbe + nbu, 256, 0, stream>>>(
        off_ent, packed, S1, relemb, n_ent, nbe,
        nullptr, nullptr, out_ent, nullptr,
        off_usr, sorted_iw, su1, n_usr,
        nullptr, out_usr, nullptr,
        ebf1, w_all);
}

// Round 12
// 327.953 us; speedup vs baseline: 2.9758x; 1.1885x over previous
//
#include <hip/hip_runtime.h>

// ---------- helpers ----------

__device__ __forceinline__ float red16(float p) {
    p += __shfl_xor(p, 1, 64);
    p += __shfl_xor(p, 2, 64);
    p += __shfl_xor(p, 4, 64);
    p += __shfl_xor(p, 8, 64);
    return p;
}

__device__ __forceinline__ float bf2f(unsigned short v) {
    return __uint_as_float(((unsigned int)v) << 16);
}
__device__ __forceinline__ unsigned short f2bf(float f) {
    unsigned int u = __float_as_uint(f);
    u = (u + 0x7FFFu + ((u >> 16) & 1u)) >> 16;
    return (unsigned short)u;
}
__device__ __forceinline__ float4 bfx4(ushort4 u) {
    return make_float4(bf2f(u.x), bf2f(u.y), bf2f(u.z), bf2f(u.w));
}
__device__ __forceinline__ float dot4(float4 a, float4 b) {
    return a.x * b.x + a.y * b.y + a.z * b.z + a.w * b.w;
}
__device__ __forceinline__ void fma4r(float4& a, float w, float4 f, float4 v) {
    a.x = fmaf(w, f.x * v.x, a.x);
    a.y = fmaf(w, f.y * v.y, a.y);
    a.z = fmaf(w, f.z * v.z, a.z);
    a.w = fmaf(w, f.w * v.w, a.w);
}
__device__ __forceinline__ void fma4(float4& a, float w, float4 f) {
    a.x = fmaf(w, f.x, a.x);
    a.y = fmaf(w, f.y, a.y);
    a.z = fmaf(w, f.z, a.z);
    a.w = fmaf(w, f.w, a.w);
}

// ---------- setup: compute_w (block 0) + hist-with-rank (rest) ----------
// rank[e] = atomicAdd(deg[dst],1) is recorded so the later scatter needs
// NO atomics (off[dst]+rank[e] is an exact unique slot).

__global__ void setup_kernel(const float* __restrict__ WQ,
                             const float* __restrict__ WUI,
                             const float* __restrict__ relemb,
                             const int* __restrict__ etype, int Ekg,
                             float* __restrict__ w_all,
                             const int* __restrict__ head,
                             unsigned int* __restrict__ deg_ent,
                             unsigned int* __restrict__ rank_e,
                             const int* __restrict__ uu, int Eui,
                             unsigned int* __restrict__ deg_usr,
                             unsigned int* __restrict__ rank_u) {
    if (blockIdx.x == 0) {
        for (int tid = threadIdx.x; tid < 640; tid += blockDim.x) {
            int r = tid >> 6, k = tid & 63;
            const float* M = (r == 9) ? WUI : WQ;
            int rr = (r == 9) ? (etype[Ekg - 1] - 1) : r;
            float acc = 0.f;
#pragma unroll
            for (int c = 0; c < 64; ++c)
                acc = fmaf(M[k * 64 + c], relemb[rr * 64 + c], acc);
            w_all[r * 64 + k] = acc;
        }
        return;
    }
    int e = (blockIdx.x - 1) * blockDim.x + threadIdx.x;
    if (e < Ekg) {
        rank_e[e] = atomicAdd(&deg_ent[head[e]], 1u);
    } else if (e < Ekg + Eui) {
        int e2 = e - Ekg;
        rank_u[e2] = atomicAdd(&deg_usr[uu[e2]], 1u);
    }
}

// ---------- scans (merged ent+usr) ----------

#define SCAN_CHUNK 2048

__device__ __forceinline__ void scan1_body(const unsigned int* deg, int n,
                                           unsigned int* bsums, int blk) {
    int base = blk * SCAN_CHUNK;
    int tid = threadIdx.x;
    unsigned int s = 0;
#pragma unroll
    for (int j = 0; j < 8; ++j) {
        int i = base + tid * 8 + j;
        if (i < n) s += deg[i];
    }
#pragma unroll
    for (int off = 32; off > 0; off >>= 1)
        s += __shfl_xor(s, off, 64);
    __shared__ unsigned int wsm[4];
    if ((tid & 63) == 0) wsm[tid >> 6] = s;
    __syncthreads();
    if (tid == 0) bsums[blk] = wsm[0] + wsm[1] + wsm[2] + wsm[3];
}

__global__ void scan_pass1(const unsigned int* __restrict__ dega, int na, int nba,
                           unsigned int* __restrict__ bsa,
                           const unsigned int* __restrict__ degb, int nb_,
                           unsigned int* __restrict__ bsb) {
    if ((int)blockIdx.x < nba) scan1_body(dega, na, bsa, blockIdx.x);
    else scan1_body(degb, nb_, bsb, blockIdx.x - nba);
}

__device__ __forceinline__ void scan2_body(unsigned int* bsums, int nb) {
    __shared__ unsigned int tmp[1024];
    int tid = threadIdx.x;
    unsigned int v = (tid < nb) ? bsums[tid] : 0u;
    tmp[tid] = v;
    __syncthreads();
    for (int s = 1; s < 1024; s <<= 1) {
        unsigned int add = (tid >= s) ? tmp[tid - s] : 0u;
        __syncthreads();
        tmp[tid] += add;
        __syncthreads();
    }
    if (tid < nb) bsums[tid] = tmp[tid] - v; // exclusive
}

__global__ void scan_pass2(unsigned int* __restrict__ bsa, int nba,
                           unsigned int* __restrict__ bsb, int nbb) {
    if (blockIdx.x == 0) scan2_body(bsa, nba);
    else scan2_body(bsb, nbb);
}

__device__ __forceinline__ void scan3_body(const unsigned int* deg, int n,
                                           const unsigned int* bsums,
                                           unsigned int* off, int blk) {
    int base = blk * SCAN_CHUNK;
    int tid = threadIdx.x;
    int lane = tid & 63, wv = tid >> 6;
    unsigned int x[8];
    unsigned int s = 0;
#pragma unroll
    for (int j = 0; j < 8; ++j) {
        int i = base + tid * 8 + j;
        x[j] = (i < n) ? deg[i] : 0u;
        s += x[j];
    }
    unsigned int sc = s;
#pragma unroll
    for (int o = 1; o < 64; o <<= 1) {
        unsigned int t = __shfl_up(sc, o, 64);
        if (lane >= o) sc += t;
    }
    __shared__ unsigned int wtot[4];
    if (lane == 63) wtot[wv] = sc;
    __syncthreads();
    unsigned int woff = 0;
    for (int w = 0; w < wv; ++w) woff += wtot[w];
    unsigned int run = bsums[blk] + woff + (sc - s);
#pragma unroll
    for (int j = 0; j < 8; ++j) {
        int i = base + tid * 8 + j;
        run += x[j];
        if (i < n) off[i + 1] = run;
    }
    if (blk == 0 && tid == 0) off[0] = 0;
}

__global__ void scan_pass3(const unsigned int* __restrict__ dega, int na, int nba,
                           const unsigned int* __restrict__ bsa,
                           unsigned int* __restrict__ offa,
                           const unsigned int* __restrict__ degb, int nb_,
                           const unsigned int* __restrict__ bsb,
                           unsigned int* __restrict__ offb) {
    if ((int)blockIdx.x < nba) scan3_body(dega, na, bsa, offa, blockIdx.x);
    else scan3_body(degb, nb_, bsb, offb, blockIdx.x - nba);
}

// ---------- merged atomic-free scatter + tables ----------

__global__ void scatter_tables_kernel(
    const int* __restrict__ head, const int* __restrict__ tail,
    const int* __restrict__ etype, int Ekg,
    const unsigned int* __restrict__ off_e,
    const unsigned int* __restrict__ rank_e,
    unsigned int* __restrict__ packed,
    const int* __restrict__ uu, const int* __restrict__ ii,
    const float* __restrict__ iw, int Eui,
    const unsigned int* __restrict__ off_u,
    const unsigned int* __restrict__ rank_u,
    unsigned long long* __restrict__ sorted_iw,
    int nsc,
    const float* __restrict__ E, int n_ent, int nbe,
    const float* __restrict__ U, int n_usr,
    const float* __restrict__ w_all,
    float* __restrict__ S, float* __restrict__ su,
    unsigned short* __restrict__ Ebf) {
    if ((int)blockIdx.x < nsc) {
        int e = blockIdx.x * blockDim.x + threadIdx.x;
        if (e < Ekg) {
            int h = head[e];
            unsigned int pos = off_e[h] + rank_e[e];
            packed[pos] = (unsigned int)tail[e] |
                          (((unsigned int)(etype[e] - 1)) << 20);
        } else if (e < Ekg + Eui) {
            int e2 = e - Ekg;
            int u = uu[e2];
            unsigned int pos = off_u[u] + rank_u[e2];
            sorted_iw[pos] =
                ((unsigned long long)__float_as_uint(iw[e2]) << 32) |
                (unsigned int)ii[e2];
        }
        return;
    }
    __shared__ float4 w4[160];
    for (int i = threadIdx.x; i < 160; i += blockDim.x)
        w4[i] = ((const float4*)w_all)[i];
    __syncthreads();
    int l16 = threadIdx.x & 15;
    int bb = blockIdx.x - nsc;
    if (bb < nbe) {
        int row = bb * 16 + (threadIdx.x >> 4);
        float4 ev = make_float4(0.f, 0.f, 0.f, 0.f);
        if (row < n_ent) {
            ev = ((const float4*)E)[(size_t)row * 16 + l16];
            ushort4 eb;
            eb.x = f2bf(ev.x); eb.y = f2bf(ev.y);
            eb.z = f2bf(ev.z); eb.w = f2bf(ev.w);
            ((ushort4*)Ebf)[(size_t)row * 16 + l16] = eb;
        }
#pragma unroll
        for (int r = 0; r < 10; ++r) {
            float4 wv = w4[r * 16 + l16];
            float p = red16(dot4(ev, wv));
            if (l16 == 0 && row < n_ent) S[(size_t)row * 10 + r] = p;
        }
    } else {
        int row = (bb - nbe) * 16 + (threadIdx.x >> 4);
        float4 ev = make_float4(0.f, 0.f, 0.f, 0.f);
        if (row < n_usr) ev = ((const float4*)U)[(size_t)row * 16 + l16];
        float p = red16(dot4(ev, w4[144 + l16]));
        if (l16 == 0 && row < n_usr) su[row] = p;
    }
}

// ---------- fused per-hop aggregation: kg blocks then ui blocks ----------
// 16-lane group per destination row. Tail scores computed ON THE FLY from
// the gathered bf16 row (d = row . w_r via red16) — no per-edge random
// S-table reads. Head score via S[h] (one line per group). No
// max-subtraction (scores bounded; exp safe in fp32 — verified R7/R8).

__global__ void hop_fused_kernel(
    const unsigned int* __restrict__ off_e,
    const unsigned int* __restrict__ packed,
    const float* __restrict__ S,
    const float* __restrict__ relemb,
    int n_ent, int nbe,
    unsigned short* __restrict__ eagg_bf, float* __restrict__ Snext,
    float* __restrict__ res_e, const float* __restrict__ res_init_e,
    const unsigned int* __restrict__ off_u,
    const unsigned long long* __restrict__ sorted_iw,
    const float* __restrict__ su, int n_usr,
    float* __restrict__ sunext,
    float* __restrict__ res_u, const float* __restrict__ res_init_u,
    const unsigned short* __restrict__ Ebf,
    const float* __restrict__ w_all) {
    __shared__ float4 rel4[144]; // 9 x 16
    __shared__ float4 w4[160];   // 10 x 16
    for (int i = threadIdx.x; i < 144; i += blockDim.x)
        rel4[i] = ((const float4*)relemb)[i];
    for (int i = threadIdx.x; i < 160; i += blockDim.x)
        w4[i] = ((const float4*)w_all)[i];
    __syncthreads();

    int lane = threadIdx.x & 63;
    int l16 = lane & 15;
    int gbase = lane & 48; // group base within wave for shfl

    if ((int)blockIdx.x < nbe) {
        int h = blockIdx.x * 16 + (threadIdx.x >> 4);
        if (h >= n_ent) return;
        unsigned int s0 = off_e[h], s1 = off_e[h + 1];
        float shv = (l16 < 10) ? S[(size_t)h * 10 + l16] : 0.f;

        float4 a0 = make_float4(0.f, 0.f, 0.f, 0.f);
        float4 a1 = make_float4(0.f, 0.f, 0.f, 0.f);
        float wsum = 0.f;
        for (unsigned int base = s0; base < s1; base += 16) {
            unsigned int rem = s1 - base;
            unsigned int c = rem < 16u ? rem : 16u;
            unsigned int pk = (l16 < (int)c) ? packed[base + l16] : 0u;
            unsigned int j = 0;
            for (; j + 2 <= c; j += 2) {
                unsigned int p0 = (unsigned int)__shfl((int)pk, gbase + (int)j, 64);
                unsigned int p1 = (unsigned int)__shfl((int)pk, gbase + (int)j + 1, 64);
                int t0 = p0 & 0xFFFFF, r0 = p0 >> 20;
                int t1 = p1 & 0xFFFFF, r1 = p1 >> 20;
                float4 f0 = bfx4(((const ushort4*)Ebf)[(size_t)t0 * 16 + l16]);
                float4 f1 = bfx4(((const ushort4*)Ebf)[(size_t)t1 * 16 + l16]);
                float d0 = red16(dot4(f0, w4[r0 * 16 + l16]));
                float d1 = red16(dot4(f1, w4[r1 * 16 + l16]));
                float q0 = __shfl(shv, gbase + r0, 64);
                float q1 = __shfl(shv, gbase + r1, 64);
                float wg0 = __expf(q0 + d0);
                float wg1 = __expf(q1 + d1);
                wsum += wg0 + wg1;
                fma4r(a0, wg0, f0, rel4[r0 * 16 + l16]);
                fma4r(a1, wg1, f1, rel4[r1 * 16 + l16]);
            }
            if (j < c) {
                unsigned int p0 = (unsigned int)__shfl((int)pk, gbase + (int)j, 64);
                int t0 = p0 & 0xFFFFF, r0 = p0 >> 20;
                float4 f0 = bfx4(((const ushort4*)Ebf)[(size_t)t0 * 16 + l16]);
                float d0 = red16(dot4(f0, w4[r0 * 16 + l16]));
                float q0 = __shfl(shv, gbase + r0, 64);
                float wg0 = __expf(q0 + d0);
                wsum += wg0;
                fma4r(a0, wg0, f0, rel4[r0 * 16 + l16]);
            }
        }
        float4 acc = make_float4(a0.x + a1.x, a0.y + a1.y,
                                 a0.z + a1.z, a0.w + a1.w);
        float inv = 1.f / (wsum + 1e-16f);
        float4 y = make_float4(acc.x * inv, acc.y * inv, acc.z * inv, acc.w * inv);
        float ss = red16(dot4(y, y));
        float sinv = 1.f / fmaxf(sqrtf(ss), 1e-12f);
        y.x *= sinv; y.y *= sinv; y.z *= sinv; y.w *= sinv;

        size_t ro = (size_t)h * 16 + l16;
        if (eagg_bf) {
            ushort4 yb;
            yb.x = f2bf(y.x); yb.y = f2bf(y.y);
            yb.z = f2bf(y.z); yb.w = f2bf(y.w);
            ((ushort4*)eagg_bf)[ro] = yb;
        }
        float4 b4 = res_init_e ? ((const float4*)res_init_e)[ro]
                               : ((const float4*)res_e)[ro];
        ((float4*)res_e)[ro] = make_float4(b4.x + y.x, b4.y + y.y,
                                           b4.z + y.z, b4.w + y.w);
        if (Snext) {
#pragma unroll
            for (int r2 = 0; r2 < 10; ++r2) {
                float p = red16(dot4(y, w4[r2 * 16 + l16]));
                if (l16 == 0) Snext[(size_t)h * 10 + r2] = p;
            }
        }
    } else {
        int u = (blockIdx.x - nbe) * 16 + (threadIdx.x >> 4);
        if (u >= n_usr) return;
        unsigned int s0 = off_u[u], s1 = off_u[u + 1];
        float squ = su[u];
        float4 w9v = w4[144 + l16];

        float4 a0 = make_float4(0.f, 0.f, 0.f, 0.f);
        float4 a1 = make_float4(0.f, 0.f, 0.f, 0.f);
        float wsum = 0.f;
        for (unsigned int base = s0; base < s1; base += 16) {
            unsigned int rem = s1 - base;
            unsigned int c = rem < 16u ? rem : 16u;
            unsigned long long t8 = (l16 < (int)c) ? sorted_iw[base + l16] : 0ull;
            unsigned int iv = (unsigned int)t8;
            float sw = __uint_as_float((unsigned int)(t8 >> 32));
            unsigned int j = 0;
            for (; j + 2 <= c; j += 2) {
                unsigned int i0 = (unsigned int)__shfl((int)iv, gbase + (int)j, 64);
                unsigned int i1 = (unsigned int)__shfl((int)iv, gbase + (int)j + 1, 64);
                float sw0 = __shfl(sw, gbase + (int)j, 64);
                float sw1 = __shfl(sw, gbase + (int)j + 1, 64);
                float4 f0 = bfx4(((const ushort4*)Ebf)[(size_t)i0 * 16 + l16]);
                float4 f1 = bfx4(((const ushort4*)Ebf)[(size_t)i1 * 16 + l16]);
                float d0 = red16(dot4(f0, w9v));
                float d1 = red16(dot4(f1, w9v));
                float wg0 = __expf(squ + d0);
                float wg1 = __expf(squ + d1);
                wsum += wg0 + wg1;
                fma4(a0, wg0 * sw0, f0);
                fma4(a1, wg1 * sw1, f1);
            }
            if (j < c) {
                unsigned int i0 = (unsigned int)__shfl((int)iv, gbase + (int)j, 64);
                float sw0 = __shfl(sw, gbase + (int)j, 64);
                float4 f0 = bfx4(((const ushort4*)Ebf)[(size_t)i0 * 16 + l16]);
                float d0 = red16(dot4(f0, w9v));
                float wg0 = __expf(squ + d0);
                wsum += wg0;
                fma4(a0, wg0 * sw0, f0);
            }
        }
        float4 acc = make_float4(a0.x + a1.x, a0.y + a1.y,
                                 a0.z + a1.z, a0.w + a1.w);
        float inv = 1.f / (wsum + 1e-16f);
        float4 y = make_float4(acc.x * inv, acc.y * inv, acc.z * inv, acc.w * inv);
        float ss = red16(dot4(y, y));
        float sinv = 1.f / fmaxf(sqrtf(ss), 1e-12f);
        y.x *= sinv; y.y *= sinv; y.z *= sinv; y.w *= sinv;

        size_t ro = (size_t)u * 16 + l16;
        float4 b4 = res_init_u ? ((const float4*)res_init_u)[ro]
                               : ((const float4*)res_u)[ro];
        ((float4*)res_u)[ro] = make_float4(b4.x + y.x, b4.y + y.y,
                                           b4.z + y.z, b4.w + y.w);
        if (sunext) {
            float p = red16(dot4(y, w9v));
            if (l16 == 0) sunext[u] = p;
        }
    }
}

// ---------- launch ----------

extern "C" void kernel_launch(void* const* d_in, const int* in_sizes, int n_in,
                              void* d_out, int out_size, void* d_ws, size_t ws_size,
                              hipStream_t stream) {
    const float* user_emb   = (const float*)d_in[0];
    const float* entity_emb = (const float*)d_in[1];
    const int*   edge_index = (const int*)d_in[2];
    const int*   edge_type  = (const int*)d_in[3];
    const int*   inter_edge = (const int*)d_in[4];
    const float* inter_w    = (const float*)d_in[5];
    const float* relemb     = (const float*)d_in[6];
    const float* WQ         = (const float*)d_in[7];
    const float* WUI        = (const float*)d_in[8];

    const int C = 64;
    const int n_usr = in_sizes[0] / C;
    const int n_ent = in_sizes[1] / C;
    const int Ekg   = in_sizes[3];
    const int Eui   = in_sizes[5];
    const int* head = edge_index;
    const int* tail = edge_index + Ekg;
    const int* uu   = inter_edge;
    const int* ii   = inter_edge + Eui;

    float* ws = (float*)d_ws;
    float* w_all = ws;                          ws += 640;
    float* S0    = ws;                          ws += (size_t)n_ent * 10;
    float* S1    = ws;                          ws += (size_t)n_ent * 10;
    float* su0   = ws;                          ws += n_usr;
    float* su1   = ws;                          ws += n_usr;
    unsigned int* deg_ent = (unsigned int*)ws;  ws += n_ent;
    unsigned int* deg_usr = (unsigned int*)ws;  ws += n_usr;
    unsigned int* off_ent = (unsigned int*)ws;  ws += n_ent + 1;
    unsigned int* off_usr = (unsigned int*)ws;  ws += n_usr + 1;
    unsigned int* bsum_e  = (unsigned int*)ws;  ws += 1024;
    unsigned int* bsum_u  = (unsigned int*)ws;  ws += 1024;
    unsigned int* rank_e  = (unsigned int*)ws;  ws += Ekg;
    unsigned int* rank_u  = (unsigned int*)ws;  ws += Eui;
    unsigned int* packed  = (unsigned int*)ws;  ws += Ekg;

    uintptr_t p16 = ((uintptr_t)ws + 15) & ~(uintptr_t)15;
    unsigned long long* sorted_iw = (unsigned long long*)p16;
    p16 += (size_t)Eui * 8;
    unsigned short* ebf0 = (unsigned short*)p16;
    p16 += (size_t)n_ent * 64 * 2;
    unsigned short* ebf1 = (unsigned short*)p16;

    float* out_ent = (float*)d_out;
    float* out_usr = out_ent + (size_t)n_ent * C;

    // ---- setup: compute_w + hist-with-rank ----
    hipMemsetAsync(deg_ent, 0, (size_t)(n_ent + n_usr) * sizeof(unsigned int), stream);
    setup_kernel<<<1 + (Ekg + Eui + 255) / 256, 256, 0, stream>>>(
        WQ, WUI, relemb, edge_type, Ekg, w_all,
        head, deg_ent, rank_e, uu, Eui, deg_usr, rank_u);

    // ---- scans ----
    int nb_e = (n_ent + SCAN_CHUNK - 1) / SCAN_CHUNK;
    int nb_u = (n_usr + SCAN_CHUNK - 1) / SCAN_CHUNK;
    scan_pass1<<<nb_e + nb_u, 256, 0, stream>>>(deg_ent, n_ent, nb_e, bsum_e,
                                                deg_usr, n_usr, bsum_u);
    scan_pass2<<<2, 1024, 0, stream>>>(bsum_e, nb_e, bsum_u, nb_u);
    scan_pass3<<<nb_e + nb_u, 256, 0, stream>>>(deg_ent, n_ent, nb_e, bsum_e, off_ent,
                                                deg_usr, n_usr, bsum_u, off_usr);

    // ---- atomic-free scatter merged with hop-0 tables ----
    int nsc = (Ekg + Eui + 255) / 256;
    int nbe = (n_ent + 15) / 16;
    int nbu = (n_usr + 15) / 16;
    scatter_tables_kernel<<<nsc + nbe + nbu, 256, 0, stream>>>(
        head, tail, edge_type, Ekg, off_ent, rank_e, packed,
        uu, ii, inter_w, Eui, off_usr, rank_u, sorted_iw, nsc,
        entity_emb, n_ent, nbe, user_emb, n_usr, w_all, S0, su0, ebf0);

    // ---- hop 0: emits S1/su1 + bf16 agg for hop 1; res = init + y ----
    hop_fused_kernel<<<nbe + nbu, 256, 0, stream>>>(
        off_ent, packed, S0, relemb, n_ent, nbe,
        ebf1, S1, out_ent, entity_emb,
        off_usr, sorted_iw, su0, n_usr,
        su1, out_usr, user_emb,
        ebf0, w_all);

    // ---- hop 1: res += y (agg outputs dead -> skipped) ----
    hop_fused_kernel<<<nbe + nbu, 256, 0, stream>>>(
        off_ent, packed, S1, relemb, n_ent, nbe,
        nullptr, nullptr, out_ent, nullptr,
        off_usr, sorted_iw, su1, n_usr,
        nullptr, out_usr, nullptr,
        ebf1, w_all);
}